// Round 13
// baseline (141.259 us; speedup 1.0000x reference)
//
#include <hip/hip_runtime.h>
#include <math.h>

#define N_    8
#define C_    512
#define HW_   1024
#define G_    32
#define CPG_  16
#define OC3_  1536
#define LOG2E 1.44269504f

typedef _Float16 f16;
typedef f16 f16x8 __attribute__((ext_vector_type(8)));
typedef f16 f16x4 __attribute__((ext_vector_type(4)));
typedef f16 f16x2 __attribute__((ext_vector_type(2)));
typedef float f32x4 __attribute__((ext_vector_type(4)));
typedef float f32x16 __attribute__((ext_vector_type(16)));

#if __has_builtin(__builtin_amdgcn_exp2f)
#define EXP2F(x) __builtin_amdgcn_exp2f(x)
#else
#define EXP2F(x) exp2f(x)
#endif

#define GLOAD_LDS16(g, l)                                                          \
    __builtin_amdgcn_global_load_lds(                                              \
        (const __attribute__((address_space(1))) unsigned int*)(const void*)(g),   \
        (__attribute__((address_space(3))) unsigned int*)(void*)(l), 16, 0, 0)

// s_waitcnt encodings: vmcnt in [3:0], expcnt=7 (no wait) in [6:4],
// lgkmcnt=15 (no wait) in [11:8]  ->  0x0F70 | vmcnt
#define WAIT_VM0() __builtin_amdgcn_s_waitcnt(0x0F70)

// ---------------- prep: GroupNorm+transpose (blocks 0..255) | weight pack (rest)
// XCD-ALIGNED: n = blk&7 so XCD(blk%8) == n -> XT[n] is written into the same
// XCD L2 that gemm<false> (n = flat&7) reads it from.
__global__ __launch_bounds__(256) void prep(const float* __restrict__ x,
                                            const float* __restrict__ gw,
                                            const float* __restrict__ gb,
                                            f16* __restrict__ XT,
                                            const float* __restrict__ qkv_w,
                                            const float* __restrict__ out_w,
                                            const float* __restrict__ qkv_b,
                                            f16* __restrict__ Wq,
                                            f16* __restrict__ Wo,
                                            float* __restrict__ qkv_bs) {
    __shared__ float red1[4], red2[4];
    __shared__ float sm, srstd;
    if (blockIdx.x >= 256) {   // ---- weight pack path ----
        const float QS = 0.125f * LOG2E;
        int idx = (blockIdx.x - 256) * 256 + threadIdx.x;
        if (idx < 786432) {
            float v = qkv_w[idx];
            if (idx < 262144) v *= QS;              // q rows (o < 512)
            Wq[idx] = (f16)v;
        } else if (idx < 786432 + 262144) {
            Wo[idx - 786432] = (f16)out_w[idx - 786432];
        } else if (idx < 786432 + 262144 + 1536) {
            int i = idx - 786432 - 262144;
            float v = qkv_b[i];
            if (i < 512) v *= QS;
            qkv_bs[i] = v;
        }
        return;
    }
    // ---- GroupNorm path ----  (XCD-aligned: n = blk&7)
    int blk = blockIdx.x;
    int n = blk & 7, g = blk >> 3;
    size_t base = ((size_t)n * C_ + (size_t)g * CPG_) * HW_;
    const float4* xp4 = (const float4*)(x + base);
    float4 vals[16];
    float s1 = 0.f, s2 = 0.f;
#pragma unroll
    for (int r = 0; r < 16; r++) {
        float4 v = xp4[r * 256 + threadIdx.x];   // c_local = r, l = 4*tid..4*tid+3
        vals[r] = v;
        s1 += v.x + v.y + v.z + v.w;
        s2 += v.x * v.x + v.y * v.y + v.z * v.z + v.w * v.w;
    }
#pragma unroll
    for (int off = 32; off > 0; off >>= 1) {
        s1 += __shfl_down(s1, off, 64);
        s2 += __shfl_down(s2, off, 64);
    }
    int wave = threadIdx.x >> 6, lane = threadIdx.x & 63;
    if (lane == 0) { red1[wave] = s1; red2[wave] = s2; }
    __syncthreads();
    if (threadIdx.x == 0) {
        float t1 = red1[0] + red1[1] + red1[2] + red1[3];
        float t2 = red2[0] + red2[1] + red2[2] + red2[3];
        float mean = t1 * (1.f / 16384.f);
        float var  = t2 * (1.f / 16384.f) - mean * mean;
        sm = mean;
        srstd = rsqrtf(var + 1e-5f);
    }
    __syncthreads();
    float mean = sm, rstd = srstd;
    float av[16], bbv[16];
#pragma unroll
    for (int r = 0; r < 16; r++) {
        int c = g * CPG_ + r;
        av[r] = gw[c] * rstd;
        bbv[r] = gb[c] - mean * av[r];
    }
    f16x8 lo[4], hi[4];
#pragma unroll
    for (int r = 0; r < 16; r++) {
        float4 v = vals[r];
        float a = av[r], bb = bbv[r];
        f16 e0 = (f16)(v.x * a + bb), e1 = (f16)(v.y * a + bb);
        f16 e2 = (f16)(v.z * a + bb), e3 = (f16)(v.w * a + bb);
        if (r < 8) { lo[0][r] = e0; lo[1][r] = e1; lo[2][r] = e2; lo[3][r] = e3; }
        else { hi[0][r - 8] = e0; hi[1][r - 8] = e1; hi[2][r - 8] = e2; hi[3][r - 8] = e3; }
    }
    // blocked store: [n][g][l][16], each thread 4 l's x 32 B contiguous = 128 B
    f16* xt = XT + (size_t)n * C_ * HW_ + ((size_t)g * HW_ + threadIdx.x * 4) * 16;
#pragma unroll
    for (int comp = 0; comp < 4; comp++) {
        *(f16x8*)&xt[comp * 16]     = lo[comp];
        *(f16x8*)&xt[comp * 16 + 8] = hi[comp];
    }
}

// ---------------- fp16 MFMA GEMM, depth-2 DMA pipeline, counted vmcnt ---------
// Y[o][l] = sum_c A[o][c] * B[...] + bias. BK=32, 16 K-steps, 3 LDS buffers.
// n = flat&7 -> XCD(flat%8) == n: per-batch tensors stay in their XCD's L2.
// V output (o0>=1024) keeps the within-16 column permutation (swap bits 2,3)
// for attn's PV x32 in-register layout.
template <bool FINAL>
__global__ __launch_bounds__(256, 4) void gemm_f16(const f16* __restrict__ A,
                                                   const f16* __restrict__ B,
                                                   const float* __restrict__ bias,
                                                   void* __restrict__ Yq,
                                                   f16* __restrict__ Yv) {
    constexpr int BM = FINAL ? 64 : 128;
    constexpr int MI = BM / 32;            // 16-row blocks per wave (wave owns BM/2)
    constexpr int ABUF = BM * 32 * 2;      // bytes per A buffer
    constexpr int BBUF = 128 * 32 * 2;     // 8192 bytes per B buffer
    constexpr int G = (BM / 64) + 2;       // per-thread GLOADs per stage
    constexpr size_t BSTEP = FINAL ? 32 : 32768;   // B-addr advance per K-step
    __shared__ __align__(16) unsigned char smem[3 * ABUF + 3 * BBUF];
    int tid = threadIdx.x, lane = tid & 63, w = tid >> 6;
    int m = lane & 15, quad = lane >> 4;
    int ow0 = (w & 1) * (BM / 2), lw0 = (w >> 1) * 64;
    int flat = blockIdx.x;
    int n = flat & 7, rest = flat >> 3;
    int l0 = (rest & 7) * 128, o0 = (rest >> 3) * BM;
    const f16* Bn = B + (size_t)n * C_ * HW_;   // 512*1024 elements either layout

    // hoisted per-thread staging offsets (element units)
    size_t aOff[BM / 64], bOff[2];
#pragma unroll
    for (int it = 0; it < BM / 64; it++) {
        int q = it * 256 + tid;
        int row = q >> 2, sg = (q & 3) ^ ((row >> 1) & 3);
        aOff[it] = (size_t)(o0 + row) * 512 + sg * 8;
    }
#pragma unroll
    for (int it = 0; it < 2; it++) {
        int q = it * 256 + tid;
        int row = q >> 2, sg = (q & 3) ^ ((row >> 1) & 3);
        if (FINAL) bOff[it] = (size_t)(l0 + row) * 512 + sg * 8;
        else       bOff[it] = (size_t)(sg >> 1) * (HW_ * 16) +
                              (size_t)(l0 + row) * 16 + (sg & 1) * 8;
    }

    f32x4 acc[MI][4];
#pragma unroll
    for (int i = 0; i < MI; i++)
#pragma unroll
        for (int j = 0; j < 4; j++)
#pragma unroll
            for (int r = 0; r < 4; r++) acc[i][j][r] = 0.f;

#define STAGE_STEP(cs_, pb_)                                                       \
    do {                                                                           \
        _Pragma("unroll")                                                          \
        for (int it = 0; it < BM / 64; it++)                                       \
            GLOAD_LDS16(A + aOff[it] + (size_t)(cs_) * 32,                         \
                        (f16*)(smem + (pb_) * ABUF) + (size_t)(it * 256 + w * 64) * 8); \
        _Pragma("unroll")                                                          \
        for (int it = 0; it < 2; it++)                                             \
            GLOAD_LDS16(Bn + bOff[it] + (size_t)(cs_) * BSTEP,                     \
                        (f16*)(smem + 3 * ABUF + (pb_) * BBUF) +                   \
                            (size_t)(it * 256 + w * 64) * 8);                      \
    } while (0)

    STAGE_STEP(0, 0);                       // prologue: tiles 0 and 1 in flight
    STAGE_STEP(1, 1);

    int p = 0, pn = 2;                      // buffer of tile cs / tile cs+2
    for (int cs = 0; cs < 16; cs++) {
        if (cs < 15) __builtin_amdgcn_s_waitcnt(0x0F70 | G);  // tile cs landed
        else         WAIT_VM0();                              // tail: only G left
        __builtin_amdgcn_s_barrier();       // all waves certified + done reading
        if (cs + 2 < 16) STAGE_STEP(cs + 2, pn);
        const f16* Asp = (const f16*)(smem + p * ABUF);
        const f16* Bsp = (const f16*)(smem + 3 * ABUF + p * BBUF);
        f16x8 af[MI], bf[4];
#pragma unroll
        for (int ib = 0; ib < MI; ib++) {
            int row = ow0 + ib * 16 + m;
            int sg = quad ^ ((row >> 1) & 3);
            af[ib] = *(const f16x8*)&Asp[row * 32 + sg * 8];
        }
#pragma unroll
        for (int jb = 0; jb < 4; jb++) {
            int row = lw0 + jb * 16 + m;
            int sg = quad ^ ((row >> 1) & 3);
            bf[jb] = *(const f16x8*)&Bsp[row * 32 + sg * 8];
        }
        __builtin_amdgcn_s_setprio(1);
#pragma unroll
        for (int ib = 0; ib < MI; ib++)
#pragma unroll
            for (int jb = 0; jb < 4; jb++)
                acc[ib][jb] = __builtin_amdgcn_mfma_f32_16x16x32_f16(
                    af[ib], bf[jb], acc[ib][jb], 0, 0, 0);
        __builtin_amdgcn_s_setprio(0);
        p  = (p  == 2) ? 0 : p + 1;
        pn = (pn == 2) ? 0 : pn + 1;
    }
#undef STAGE_STEP

    float bv[MI][4];
#pragma unroll
    for (int ib = 0; ib < MI; ib++)
#pragma unroll
        for (int r = 0; r < 4; r++)
            bv[ib][r] = bias[o0 + ow0 + ib * 16 + quad * 4 + r];

    if (FINAL) {
        float* on = (float*)Yq + (size_t)n * C_ * HW_;
#pragma unroll
        for (int ib = 0; ib < MI; ib++)
#pragma unroll
            for (int jb = 0; jb < 4; jb++)
#pragma unroll
                for (int r = 0; r < 4; r++)
                    on[(size_t)(o0 + ow0 + ib * 16 + quad * 4 + r) * HW_ +
                       l0 + lw0 + jb * 16 + m] = acc[ib][jb][r] + bv[ib][r];
    } else if (o0 >= 1024) {
        // V output: permute within-16 column (swap bits 2,3) for attn PV layout
        int mp = (m & 3) | ((m & 4) << 1) | ((m & 8) >> 1);
        f16* vn = Yv + (size_t)n * C_ * HW_;
#pragma unroll
        for (int ib = 0; ib < MI; ib++)
#pragma unroll
            for (int jb = 0; jb < 4; jb++)
#pragma unroll
                for (int r = 0; r < 4; r++)
                    vn[(size_t)(o0 - 1024 + ow0 + ib * 16 + quad * 4 + r) * HW_ +
                       l0 + lw0 + jb * 16 + mp] = (f16)(acc[ib][jb][r] + bv[ib][r]);
    } else {
        __syncthreads();                 // staging reads done; reuse smem
        f16* T = (f16*)smem;             // [128][136]
#pragma unroll
        for (int ib = 0; ib < MI; ib++)
#pragma unroll
            for (int jb = 0; jb < 4; jb++) {
                f16x4 h;
#pragma unroll
                for (int r = 0; r < 4; r++) h[r] = (f16)(acc[ib][jb][r] + bv[ib][r]);
                int l = lw0 + jb * 16 + m;
                int oo = ow0 + ib * 16 + quad * 4;
                *(f16x4*)&T[l * 136 + oo] = h;
            }
        __syncthreads();
        f16* qn = (f16*)Yq + (size_t)n * HW_ * 1024;
#pragma unroll
        for (int rep = 0; rep < 8; rep++) {
            int idx = rep * 256 + tid;
            int l = idx >> 4, seg = idx & 15;
            f16x8 v = *(const f16x8*)&T[l * 136 + seg * 8];
            *(f16x8*)&qn[(size_t)(l0 + l) * 1024 + o0 + seg * 8] = v;
        }
    }
}

// ---------------- Flash attention fp16, 32-row strips, 32x32x16 MFMAs --------
// (r7 compute structure.) XCD-ALIGNED BATCH MAPPING: n = xcd (was head = xcd),
// so each XCD's 64 blocks read qkvT[n]/vbuf[n] (~3 MB) from the SAME XCD L2
// that gemm<false> wrote them into, and write w2T[n] where gemm<true> reads
// it. Prior mapping spread every batch across all XCDs -> 14.8 MB HBM
// fetch/dispatch; this should collapse to L2 hits.
__global__ __launch_bounds__(256, 4) void attn_f16(const f16* __restrict__ qkvT,
                                                   const f16* __restrict__ vbuf,
                                                   f16* __restrict__ w2T) {
    __shared__ __align__(16) unsigned char smem[32768];
    f16* Kb0  = (f16*)smem;                 // two 8 KB K buffers at 0, 8192
    f16* Vb0  = (f16*)(smem + 16384);       // two 8 KB V buffers at 16384, 24576
    f16* LDSo = (f16*)smem;                 // epilogue alias (16 KB: [1024][8])

    int tid = threadIdx.x;
    int lane = tid & 63, wave = tid >> 6;
    int l31 = lane & 31, hi = lane >> 5;
    // XCD-aligned: 512 blocks; n = xcd, head/itile from slot (all bijective)
    int flat = blockIdx.x;
    int xcd = flat & 7, slot = flat >> 3;          // slot 0..63
    int n = xcd, head = slot & 7, itile = slot >> 3;
    int i0 = itile * 128;
    const f16* qb = qkvT + (size_t)n * HW_ * 1024 + head * 64;
    const f16* kb = qb + 512;
    const f16* vb = vbuf + (size_t)n * C_ * HW_ + (size_t)head * 64 * HW_;

    // Q fragments (B-operand): lane: Q[i=l31][d = dc*16 + hi*8 + e], i per wave
    f16x8 aq[4];
    {
        const f16* qr = qb + (size_t)(i0 + wave * 32 + l31) * 1024;
#pragma unroll
        for (int dc = 0; dc < 4; dc++)
            aq[dc] = *(const f16x8*)&qr[dc * 16 + hi * 8];
    }

    // stage tile 0 -> buffer 0 (async); K LDS [64 j][64 d], V LDS [64 c][64 jpos]
#pragma unroll
    for (int it = 0; it < 2; it++) {
        int chunk = it * 256 + tid;
        int row = chunk >> 3, seg = chunk & 7;
        int segg = seg ^ (row & 7);
        GLOAD_LDS16(kb + (size_t)row * 1024 + segg * 8,
                    Kb0 + ((size_t)it * 256 + wave * 64) * 8);
        GLOAD_LDS16(vb + (size_t)row * HW_ + segg * 8,
                    Vb0 + ((size_t)it * 256 + wave * 64) * 8);
    }

    f32x16 oaccD[2], oaccL;
#pragma unroll
    for (int r = 0; r < 16; r++) { oaccD[0][r] = 0.f; oaccD[1][r] = 0.f; oaccL[r] = 0.f; }
    const f16x8 vones = {(f16)1.f, (f16)1.f, (f16)1.f, (f16)1.f,
                         (f16)1.f, (f16)1.f, (f16)1.f, (f16)1.f};

    for (int jt = 0; jt < 16; jt++) {
        int p = jt & 1;
        const f16* Kp = Kb0 + p * 4096;
        const f16* Vp = Vb0 + p * 4096;
        WAIT_VM0();        // drain own LDS-DMA before the barrier
        __syncthreads();   // all waves aligned => buffer p fully written
        if (jt < 15) {     // prefetch tile jt+1 into the other buffer
            int j0n = (jt + 1) * 64;
            f16* Kn = Kb0 + (1 - p) * 4096;
            f16* Vn = Vb0 + (1 - p) * 4096;
#pragma unroll
            for (int it = 0; it < 2; it++) {
                int chunk = it * 256 + tid;
                int row = chunk >> 3, seg = chunk & 7;
                int segg = seg ^ (row & 7);
                GLOAD_LDS16(kb + (size_t)(j0n + row) * 1024 + segg * 8,
                            Kn + ((size_t)it * 256 + wave * 64) * 8);
                GLOAD_LDS16(vb + (size_t)row * HW_ + j0n + segg * 8,
                            Vn + ((size_t)it * 256 + wave * 64) * 8);
            }
        }

        // ---- QK^T (x32): S^T[jh] over j = jh*32 + ..., d chunks of 16
        f32x16 s0, s1;
#pragma unroll
        for (int r = 0; r < 16; r++) { s0[r] = 0.f; s1[r] = 0.f; }
        __builtin_amdgcn_s_setprio(1);
#pragma unroll
        for (int dc = 0; dc < 4; dc++) {
            int row0 = l31, row1 = 32 + l31;
            int seg = dc * 2 + hi;
            f16x8 kf0 = *(const f16x8*)&Kp[row0 * 64 + ((seg ^ (row0 & 7)) * 8)];
            f16x8 kf1 = *(const f16x8*)&Kp[row1 * 64 + ((seg ^ (row1 & 7)) * 8)];
            s0 = __builtin_amdgcn_mfma_f32_32x32x16_f16(kf0, aq[dc], s0, 0, 0, 0);
            s1 = __builtin_amdgcn_mfma_f32_32x32x16_f16(kf1, aq[dc], s1, 0, 0, 0);
        }
        __builtin_amdgcn_s_setprio(0);

        // ---- max-free softmax: p = 2^s (scale folded into Wq); pack P as the
        // x32 B-frag directly: chunk q element e = exp(sacc[q>>1][(q&1)*8+e])
        f16x8 pfc[4];
#pragma unroll
        for (int q = 0; q < 4; q++) {
            f32x16 sv = (q < 2) ? s0 : s1;
            int bs = (q & 1) * 8;
#pragma unroll
            for (int t = 0; t < 4; t++) {
                float a = EXP2F(sv[bs + 2 * t]);
                float b = EXP2F(sv[bs + 2 * t + 1]);
                f16x2 pk = __builtin_bit_cast(f16x2, __builtin_amdgcn_cvt_pkrtz(a, b));
                pfc[q][2 * t]     = pk[0];
                pfc[q][2 * t + 1] = pk[1];
            }
        }

        // ---- PV (x32): O^T[c][i] += V^T · P ; rowsum += ones · P (matrix pipe)
        __builtin_amdgcn_s_setprio(1);
#pragma unroll
        for (int q = 0; q < 4; q++) {
            oaccL = __builtin_amdgcn_mfma_f32_32x32x16_f16(vones, pfc[q],
                                                           oaccL, 0, 0, 0);
#pragma unroll
            for (int t = 0; t < 2; t++) {
                int c = t * 32 + l31;
                int seg = q * 2 + hi;
                f16x8 vf = *(const f16x8*)&Vp[c * 64 + ((seg ^ (c & 7)) * 8)];
                oaccD[t] = __builtin_amdgcn_mfma_f32_32x32x16_f16(vf, pfc[q],
                                                                  oaccD[t], 0, 0, 0);
            }
        }
        __builtin_amdgcn_s_setprio(0);
    }

    // lane holds O^T[c][i=l31] for 32 c's; rowsum in oaccL (all regs equal)
    float linv = 1.f / oaccL[0];

    WAIT_VM0();
    __syncthreads();   // everyone done with K/V buffers before aliasing
    // torch-reshape epilogue: global ch = head*64 + (i>>4); s = (i&15)*64 + cc
    // block covers 8 consecutive ch -> LDSo [1024 s][8 ch-slot]
#pragma unroll
    for (int t = 0; t < 2; t++)
#pragma unroll
        for (int r = 0; r < 16; r++) {
            int cc = t * 32 + (r & 3) + 8 * (r >> 2) + 4 * hi;
            int il = wave * 32 + l31;
            int sc = (il & 15) * 64 + cc;
            LDSo[sc * 8 + (il >> 4)] = (f16)(oaccD[t][r] * linv);
        }
    __syncthreads();
    f16* w2n = w2T + (size_t)n * HW_ * 512;
    int chbase = head * 64 + itile * 8;     // 8-aligned -> 16B-aligned stores
#pragma unroll
    for (int it = 0; it < 4; it++) {
        int sc = it * 256 + tid;
        *(f16x8*)&w2n[(size_t)sc * 512 + chbase] = *(const f16x8*)&LDSo[sc * 8];
    }
}

extern "C" void kernel_launch(void* const* d_in, const int* in_sizes, int n_in,
                              void* d_out, int out_size, void* d_ws, size_t ws_size,
                              hipStream_t stream) {
    (void)in_sizes; (void)n_in; (void)out_size; (void)ws_size;
    const float* x     = (const float*)d_in[0];
    const float* gw    = (const float*)d_in[1];
    const float* gb    = (const float*)d_in[2];
    const float* qkv_w = (const float*)d_in[3];
    const float* qkv_b = (const float*)d_in[4];
    const float* out_w = (const float*)d_in[5];
    const float* out_b = (const float*)d_in[6];
    float* out = (float*)d_out;
    char* ws = (char*)d_ws;

    const size_t MB = 1024 * 1024;
    f16*   qkvT   = (f16*)ws;                       // [8][1024][1024] q|k  (16 MB)
    f16*   XT     = (f16*)(ws + 16 * MB);           // blocked [8][32][1024][16] (8 MB)
    f16*   vbuf   = (f16*)(ws + 24 * MB);           // [8][512][1024] (j-permuted) (8 MB)
    f16*   w2T    = (f16*)(ws + 32 * MB);           // [8][1024][512]       (8 MB)
    f16*   Wq     = (f16*)(ws + 40 * MB);           // [1536][512]          (1.5 MB)
    f16*   Wo     = (f16*)(ws + 42 * MB);           // [512][512]           (0.5 MB)
    float* qkv_bs = (float*)(ws + 43 * MB);         // [1536]

    prep<<<dim3(256 + 4103), 256, 0, stream>>>(x, gw, gb, XT,
                                               qkv_w, out_w, qkv_b, Wq, Wo, qkv_bs);
    gemm_f16<false><<<dim3(768), 256, 0, stream>>>(Wq, XT, qkv_bs, (void*)qkvT, vbuf);
    attn_f16<<<dim3(512), 256, 0, stream>>>(qkvT, vbuf, w2T);
    gemm_f16<true><<<dim3(512), 256, 0, stream>>>(Wo, w2T, out_b, (void*)out, nullptr);
}

// Round 14
// 138.096 us; speedup vs baseline: 1.0229x; 1.0229x over previous
//
#include <hip/hip_runtime.h>
#include <math.h>

#define N_    8
#define C_    512
#define HW_   1024
#define G_    32
#define CPG_  16
#define OC3_  1536
#define LOG2E 1.44269504f

typedef _Float16 f16;
typedef f16 f16x8 __attribute__((ext_vector_type(8)));
typedef f16 f16x4 __attribute__((ext_vector_type(4)));
typedef f16 f16x2 __attribute__((ext_vector_type(2)));
typedef float f32x4 __attribute__((ext_vector_type(4)));
typedef float f32x16 __attribute__((ext_vector_type(16)));

#if __has_builtin(__builtin_amdgcn_exp2f)
#define EXP2F(x) __builtin_amdgcn_exp2f(x)
#else
#define EXP2F(x) exp2f(x)
#endif

#define GLOAD_LDS16(g, l)                                                          \
    __builtin_amdgcn_global_load_lds(                                              \
        (const __attribute__((address_space(1))) unsigned int*)(const void*)(g),   \
        (__attribute__((address_space(3))) unsigned int*)(void*)(l), 16, 0, 0)

// s_waitcnt encodings: vmcnt in [3:0], expcnt=7 (no wait) in [6:4],
// lgkmcnt=15 (no wait) in [11:8]  ->  0x0F70 | vmcnt
#define WAIT_VM0() __builtin_amdgcn_s_waitcnt(0x0F70)

// ---------------- prep: GroupNorm+transpose (blocks 0..255) | weight pack (rest)
__global__ __launch_bounds__(256) void prep(const float* __restrict__ x,
                                            const float* __restrict__ gw,
                                            const float* __restrict__ gb,
                                            f16* __restrict__ XT,
                                            const float* __restrict__ qkv_w,
                                            const float* __restrict__ out_w,
                                            const float* __restrict__ qkv_b,
                                            f16* __restrict__ Wq,
                                            f16* __restrict__ Wo,
                                            float* __restrict__ qkv_bs) {
    __shared__ float red1[4], red2[4];
    __shared__ float sm, srstd;
    if (blockIdx.x >= 256) {   // ---- weight pack path ----
        const float QS = 0.125f * LOG2E;
        int idx = (blockIdx.x - 256) * 256 + threadIdx.x;
        if (idx < 786432) {
            float v = qkv_w[idx];
            if (idx < 262144) v *= QS;              // q rows (o < 512)
            Wq[idx] = (f16)v;
        } else if (idx < 786432 + 262144) {
            Wo[idx - 786432] = (f16)out_w[idx - 786432];
        } else if (idx < 786432 + 262144 + 1536) {
            int i = idx - 786432 - 262144;
            float v = qkv_b[i];
            if (i < 512) v *= QS;
            qkv_bs[i] = v;
        }
        return;
    }
    // ---- GroupNorm path ----
    int blk = blockIdx.x;
    int n = blk >> 5, g = blk & 31;
    size_t base = ((size_t)n * C_ + (size_t)g * CPG_) * HW_;
    const float4* xp4 = (const float4*)(x + base);
    float4 vals[16];
    float s1 = 0.f, s2 = 0.f;
#pragma unroll
    for (int r = 0; r < 16; r++) {
        float4 v = xp4[r * 256 + threadIdx.x];   // c_local = r, l = 4*tid..4*tid+3
        vals[r] = v;
        s1 += v.x + v.y + v.z + v.w;
        s2 += v.x * v.x + v.y * v.y + v.z * v.z + v.w * v.w;
    }
#pragma unroll
    for (int off = 32; off > 0; off >>= 1) {
        s1 += __shfl_down(s1, off, 64);
        s2 += __shfl_down(s2, off, 64);
    }
    int wave = threadIdx.x >> 6, lane = threadIdx.x & 63;
    if (lane == 0) { red1[wave] = s1; red2[wave] = s2; }
    __syncthreads();
    if (threadIdx.x == 0) {
        float t1 = red1[0] + red1[1] + red1[2] + red1[3];
        float t2 = red2[0] + red2[1] + red2[2] + red2[3];
        float mean = t1 * (1.f / 16384.f);
        float var  = t2 * (1.f / 16384.f) - mean * mean;
        sm = mean;
        srstd = rsqrtf(var + 1e-5f);
    }
    __syncthreads();
    float mean = sm, rstd = srstd;
    float av[16], bbv[16];
#pragma unroll
    for (int r = 0; r < 16; r++) {
        int c = g * CPG_ + r;
        av[r] = gw[c] * rstd;
        bbv[r] = gb[c] - mean * av[r];
    }
    f16x8 lo[4], hi[4];
#pragma unroll
    for (int r = 0; r < 16; r++) {
        float4 v = vals[r];
        float a = av[r], bb = bbv[r];
        f16 e0 = (f16)(v.x * a + bb), e1 = (f16)(v.y * a + bb);
        f16 e2 = (f16)(v.z * a + bb), e3 = (f16)(v.w * a + bb);
        if (r < 8) { lo[0][r] = e0; lo[1][r] = e1; lo[2][r] = e2; lo[3][r] = e3; }
        else { hi[0][r - 8] = e0; hi[1][r - 8] = e1; hi[2][r - 8] = e2; hi[3][r - 8] = e3; }
    }
    // blocked store: [n][g][l][16], each thread 4 l's x 32 B contiguous = 128 B
    f16* xt = XT + (size_t)n * C_ * HW_ + ((size_t)g * HW_ + threadIdx.x * 4) * 16;
#pragma unroll
    for (int comp = 0; comp < 4; comp++) {
        *(f16x8*)&xt[comp * 16]     = lo[comp];
        *(f16x8*)&xt[comp * 16 + 8] = hi[comp];
    }
}

// ---------------- fp16 MFMA GEMM, depth-2 DMA pipeline, counted vmcnt ---------
// Y[o][l] = sum_c A[o][c] * B[...] + bias. BK=32, 16 K-steps, 3 LDS buffers.
// Step k: waitcnt vmcnt(G) certifies tile k landed (k+1 in flight); raw
// s_barrier collectivizes; stage tile k+2; compute tile k (T4).
// V output (o0>=1024) is written with the within-16 column permutation
// l -> swap(bit2,bit3): attn's PV x32 k-order then matches P's natural lane
// layout with ZERO cross-lane movement (permutation folded into V layout).
template <bool FINAL>
__global__ __launch_bounds__(256, 4) void gemm_f16(const f16* __restrict__ A,
                                                   const f16* __restrict__ B,
                                                   const float* __restrict__ bias,
                                                   void* __restrict__ Yq,
                                                   f16* __restrict__ Yv) {
    constexpr int BM = FINAL ? 64 : 128;
    constexpr int MI = BM / 32;            // 16-row blocks per wave (wave owns BM/2)
    constexpr int ABUF = BM * 32 * 2;      // bytes per A buffer
    constexpr int BBUF = 128 * 32 * 2;     // 8192 bytes per B buffer
    constexpr int G = (BM / 64) + 2;       // per-thread GLOADs per stage
    __shared__ __align__(16) unsigned char smem[3 * ABUF + 3 * BBUF];
    int tid = threadIdx.x, lane = tid & 63, w = tid >> 6;
    int m = lane & 15, quad = lane >> 4;
    int ow0 = (w & 1) * (BM / 2), lw0 = (w >> 1) * 64;
    int flat = blockIdx.x;
    int n = flat & 7, rest = flat >> 3;
    int l0 = (rest & 7) * 128, o0 = (rest >> 3) * BM;
    const f16* Bn = B + (size_t)n * C_ * HW_;   // 512*1024 elements either layout

    f32x4 acc[MI][4];
#pragma unroll
    for (int i = 0; i < MI; i++)
#pragma unroll
        for (int j = 0; j < 4; j++)
#pragma unroll
            for (int r = 0; r < 4; r++) acc[i][j][r] = 0.f;

#define STAGE_STEP(c0_, pb_)                                                       \
    do {                                                                           \
        _Pragma("unroll")                                                          \
        for (int it = 0; it < BM / 64; it++) {                                     \
            int q = it * 256 + tid;                                                \
            int row = q >> 2, sg = (q & 3) ^ ((row >> 1) & 3);                     \
            GLOAD_LDS16(A + (size_t)(o0 + row) * 512 + (c0_) + sg * 8,             \
                        (f16*)(smem + (pb_) * ABUF) + (size_t)(it * 256 + w * 64) * 8); \
        }                                                                          \
        _Pragma("unroll")                                                          \
        for (int it = 0; it < 2; it++) {                                           \
            int q = it * 256 + tid;                                                \
            int row = q >> 2, sg = (q & 3) ^ ((row >> 1) & 3);                     \
            size_t baddr;                                                          \
            if (FINAL) {                                                           \
                baddr = (size_t)(l0 + row) * 512 + (c0_) + sg * 8;                 \
            } else {                                                               \
                int c = (c0_) + sg * 8;                                            \
                baddr = ((size_t)(c >> 4) * HW_ + (l0 + row)) * 16 + (c & 15);     \
            }                                                                      \
            GLOAD_LDS16(Bn + baddr,                                                \
                        (f16*)(smem + 3 * ABUF + (pb_) * BBUF) +                   \
                            (size_t)(it * 256 + w * 64) * 8);                      \
        }                                                                          \
    } while (0)

    STAGE_STEP(0, 0);                       // prologue: tiles 0 and 1 in flight
    STAGE_STEP(32, 1);

    for (int cs = 0; cs < 16; cs++) {
        int p = cs % 3;
        if (cs < 15) __builtin_amdgcn_s_waitcnt(0x0F70 | G);  // tile cs landed
        else         WAIT_VM0();                              // tail: only G left
        __builtin_amdgcn_s_barrier();       // all waves certified + done reading
        if (cs + 2 < 16) STAGE_STEP((cs + 2) * 32, (cs + 2) % 3);
        const f16* Asp = (const f16*)(smem + p * ABUF);
        const f16* Bsp = (const f16*)(smem + 3 * ABUF + p * BBUF);
        f16x8 af[MI], bf[4];
#pragma unroll
        for (int ib = 0; ib < MI; ib++) {
            int row = ow0 + ib * 16 + m;
            int sg = quad ^ ((row >> 1) & 3);
            af[ib] = *(const f16x8*)&Asp[row * 32 + sg * 8];
        }
#pragma unroll
        for (int jb = 0; jb < 4; jb++) {
            int row = lw0 + jb * 16 + m;
            int sg = quad ^ ((row >> 1) & 3);
            bf[jb] = *(const f16x8*)&Bsp[row * 32 + sg * 8];
        }
        __builtin_amdgcn_s_setprio(1);
#pragma unroll
        for (int ib = 0; ib < MI; ib++)
#pragma unroll
            for (int jb = 0; jb < 4; jb++)
                acc[ib][jb] = __builtin_amdgcn_mfma_f32_16x16x32_f16(
                    af[ib], bf[jb], acc[ib][jb], 0, 0, 0);
        __builtin_amdgcn_s_setprio(0);
    }
#undef STAGE_STEP

    float bv[MI][4];
#pragma unroll
    for (int ib = 0; ib < MI; ib++)
#pragma unroll
        for (int r = 0; r < 4; r++)
            bv[ib][r] = bias[o0 + ow0 + ib * 16 + quad * 4 + r];

    if (FINAL) {
        float* on = (float*)Yq + (size_t)n * C_ * HW_;
#pragma unroll
        for (int ib = 0; ib < MI; ib++)
#pragma unroll
            for (int jb = 0; jb < 4; jb++)
#pragma unroll
                for (int r = 0; r < 4; r++)
                    on[(size_t)(o0 + ow0 + ib * 16 + quad * 4 + r) * HW_ +
                       l0 + lw0 + jb * 16 + m] = acc[ib][jb][r] + bv[ib][r];
    } else if (o0 >= 1024) {
        // V output: permute within-16 column (swap bits 2,3) for attn PV layout
        int mp = (m & 3) | ((m & 4) << 1) | ((m & 8) >> 1);
        f16* vn = Yv + (size_t)n * C_ * HW_;
#pragma unroll
        for (int ib = 0; ib < MI; ib++)
#pragma unroll
            for (int jb = 0; jb < 4; jb++)
#pragma unroll
                for (int r = 0; r < 4; r++)
                    vn[(size_t)(o0 - 1024 + ow0 + ib * 16 + quad * 4 + r) * HW_ +
                       l0 + lw0 + jb * 16 + mp] = (f16)(acc[ib][jb][r] + bv[ib][r]);
    } else {
        __syncthreads();                 // staging reads done; reuse smem
        f16* T = (f16*)smem;             // [128][136]
#pragma unroll
        for (int ib = 0; ib < MI; ib++)
#pragma unroll
            for (int jb = 0; jb < 4; jb++) {
                f16x4 h;
#pragma unroll
                for (int r = 0; r < 4; r++) h[r] = (f16)(acc[ib][jb][r] + bv[ib][r]);
                int l = lw0 + jb * 16 + m;
                int oo = ow0 + ib * 16 + quad * 4;
                *(f16x4*)&T[l * 136 + oo] = h;
            }
        __syncthreads();
        f16* qn = (f16*)Yq + (size_t)n * HW_ * 1024;
#pragma unroll
        for (int rep = 0; rep < 8; rep++) {
            int idx = rep * 256 + tid;
            int l = idx >> 4, seg = idx & 15;
            f16x8 v = *(const f16x8*)&T[l * 136 + seg * 8];
            *(f16x8*)&qn[(size_t)(l0 + l) * 1024 + o0 + seg * 8] = v;
        }
    }
}

// ---------------- Flash attention fp16, 32-row strips, 32x32x16 MFMAs --------
// (Session-best structure, round-7 verbatim.) Wave owns 32 i-rows; block =
// 4 waves = 128 rows; grid 512 (2/CU, 32 KB LDS). QK^T: S^T = K·Q^T via x32;
// PV: O^T = V^T·P via x32 with V's k-order permuted (baked into vbuf) so the
// P B-frag is sacc regs IN ORDER — zero cross-lane movement, P never in LDS.
// Rowsum via MFMA ones on the matrix pipe; 2-buffer DMA prefetch. Deeper
// pipelines, KVBLK=128, 64-row waves, and XCD-batch-alignment all measured
// null-to-negative — this is the measured local optimum.
__global__ __launch_bounds__(256, 4) void attn_f16(const f16* __restrict__ qkvT,
                                                   const f16* __restrict__ vbuf,
                                                   f16* __restrict__ w2T) {
    __shared__ __align__(16) unsigned char smem[32768];
    f16* Kb0  = (f16*)smem;                 // two 8 KB K buffers at 0, 8192
    f16* Vb0  = (f16*)(smem + 16384);       // two 8 KB V buffers at 16384, 24576
    f16* LDSo = (f16*)smem;                 // epilogue alias (16 KB: [1024][8])

    int tid = threadIdx.x;
    int lane = tid & 63, wave = tid >> 6;
    int l31 = lane & 31, hi = lane >> 5;
    // XCD swizzle: 512 blocks; bh = bh_hi*8 + xcd
    int flat = blockIdx.x;
    int xcd = flat & 7, slot = flat >> 3;          // slot 0..63
    int itile = slot >> 3, bh = (slot & 7) * 8 + xcd;
    int n = bh >> 3, head = bh & 7;
    int i0 = itile * 128;
    const f16* qb = qkvT + (size_t)n * HW_ * 1024 + head * 64;
    const f16* kb = qb + 512;
    const f16* vb = vbuf + (size_t)n * C_ * HW_ + (size_t)head * 64 * HW_;

    // Q fragments (B-operand): lane: Q[i=l31][d = dc*16 + hi*8 + e], i per wave
    f16x8 aq[4];
    {
        const f16* qr = qb + (size_t)(i0 + wave * 32 + l31) * 1024;
#pragma unroll
        for (int dc = 0; dc < 4; dc++)
            aq[dc] = *(const f16x8*)&qr[dc * 16 + hi * 8];
    }

    // stage tile 0 -> buffer 0 (async); K LDS [64 j][64 d], V LDS [64 c][64 jpos]
#pragma unroll
    for (int it = 0; it < 2; it++) {
        int chunk = it * 256 + tid;
        int row = chunk >> 3, seg = chunk & 7;
        int segg = seg ^ (row & 7);
        GLOAD_LDS16(kb + (size_t)row * 1024 + segg * 8,
                    Kb0 + ((size_t)it * 256 + wave * 64) * 8);
        GLOAD_LDS16(vb + (size_t)row * HW_ + segg * 8,
                    Vb0 + ((size_t)it * 256 + wave * 64) * 8);
    }

    f32x16 oaccD[2], oaccL;
#pragma unroll
    for (int r = 0; r < 16; r++) { oaccD[0][r] = 0.f; oaccD[1][r] = 0.f; oaccL[r] = 0.f; }
    const f16x8 vones = {(f16)1.f, (f16)1.f, (f16)1.f, (f16)1.f,
                         (f16)1.f, (f16)1.f, (f16)1.f, (f16)1.f};

    for (int jt = 0; jt < 16; jt++) {
        int p = jt & 1;
        const f16* Kp = Kb0 + p * 4096;
        const f16* Vp = Vb0 + p * 4096;
        WAIT_VM0();        // drain own LDS-DMA before the barrier
        __syncthreads();   // all waves aligned => buffer p fully written
        if (jt < 15) {     // prefetch tile jt+1 into the other buffer
            int j0n = (jt + 1) * 64;
            f16* Kn = Kb0 + (1 - p) * 4096;
            f16* Vn = Vb0 + (1 - p) * 4096;
#pragma unroll
            for (int it = 0; it < 2; it++) {
                int chunk = it * 256 + tid;
                int row = chunk >> 3, seg = chunk & 7;
                int segg = seg ^ (row & 7);
                GLOAD_LDS16(kb + (size_t)(j0n + row) * 1024 + segg * 8,
                            Kn + ((size_t)it * 256 + wave * 64) * 8);
                GLOAD_LDS16(vb + (size_t)row * HW_ + j0n + segg * 8,
                            Vn + ((size_t)it * 256 + wave * 64) * 8);
            }
        }

        // ---- QK^T (x32): S^T[jh] over j = jh*32 + ..., d chunks of 16
        f32x16 s0, s1;
#pragma unroll
        for (int r = 0; r < 16; r++) { s0[r] = 0.f; s1[r] = 0.f; }
        __builtin_amdgcn_s_setprio(1);
#pragma unroll
        for (int dc = 0; dc < 4; dc++) {
            int row0 = l31, row1 = 32 + l31;
            int seg = dc * 2 + hi;
            f16x8 kf0 = *(const f16x8*)&Kp[row0 * 64 + ((seg ^ (row0 & 7)) * 8)];
            f16x8 kf1 = *(const f16x8*)&Kp[row1 * 64 + ((seg ^ (row1 & 7)) * 8)];
            s0 = __builtin_amdgcn_mfma_f32_32x32x16_f16(kf0, aq[dc], s0, 0, 0, 0);
            s1 = __builtin_amdgcn_mfma_f32_32x32x16_f16(kf1, aq[dc], s1, 0, 0, 0);
        }
        __builtin_amdgcn_s_setprio(0);

        // ---- max-free softmax: p = 2^s (scale folded into Wq); pack P as the
        // x32 B-frag directly: chunk q element e = exp(sacc[q>>1][(q&1)*8+e])
        f16x8 pfc[4];
#pragma unroll
        for (int q = 0; q < 4; q++) {
            f32x16 sv = (q < 2) ? s0 : s1;
            int bs = (q & 1) * 8;
#pragma unroll
            for (int t = 0; t < 4; t++) {
                float a = EXP2F(sv[bs + 2 * t]);
                float b = EXP2F(sv[bs + 2 * t + 1]);
                f16x2 pk = __builtin_bit_cast(f16x2, __builtin_amdgcn_cvt_pkrtz(a, b));
                pfc[q][2 * t]     = pk[0];
                pfc[q][2 * t + 1] = pk[1];
            }
        }

        // ---- PV (x32): O^T[c][i] += V^T · P ; rowsum += ones · P (matrix pipe)
        __builtin_amdgcn_s_setprio(1);
#pragma unroll
        for (int q = 0; q < 4; q++) {
            oaccL = __builtin_amdgcn_mfma_f32_32x32x16_f16(vones, pfc[q],
                                                           oaccL, 0, 0, 0);
#pragma unroll
            for (int t = 0; t < 2; t++) {
                int c = t * 32 + l31;
                int seg = q * 2 + hi;
                f16x8 vf = *(const f16x8*)&Vp[c * 64 + ((seg ^ (c & 7)) * 8)];
                oaccD[t] = __builtin_amdgcn_mfma_f32_32x32x16_f16(vf, pfc[q],
                                                                  oaccD[t], 0, 0, 0);
            }
        }
        __builtin_amdgcn_s_setprio(0);
    }

    // lane holds O^T[c][i=l31] for 32 c's; rowsum in oaccL (all regs equal)
    float linv = 1.f / oaccL[0];

    WAIT_VM0();
    __syncthreads();   // everyone done with K/V buffers before aliasing
    // torch-reshape epilogue: global ch = head*64 + (i>>4); s = (i&15)*64 + cc
    // block covers 8 consecutive ch -> LDSo [1024 s][8 ch-slot]
#pragma unroll
    for (int t = 0; t < 2; t++)
#pragma unroll
        for (int r = 0; r < 16; r++) {
            int cc = t * 32 + (r & 3) + 8 * (r >> 2) + 4 * hi;
            int il = wave * 32 + l31;
            int sc = (il & 15) * 64 + cc;
            LDSo[sc * 8 + (il >> 4)] = (f16)(oaccD[t][r] * linv);
        }
    __syncthreads();
    f16* w2n = w2T + (size_t)n * HW_ * 512;
    int chbase = head * 64 + itile * 8;     // 8-aligned -> 16B-aligned stores
#pragma unroll
    for (int it = 0; it < 4; it++) {
        int sc = it * 256 + tid;
        *(f16x8*)&w2n[(size_t)sc * 512 + chbase] = *(const f16x8*)&LDSo[sc * 8];
    }
}

extern "C" void kernel_launch(void* const* d_in, const int* in_sizes, int n_in,
                              void* d_out, int out_size, void* d_ws, size_t ws_size,
                              hipStream_t stream) {
    (void)in_sizes; (void)n_in; (void)out_size; (void)ws_size;
    const float* x     = (const float*)d_in[0];
    const float* gw    = (const float*)d_in[1];
    const float* gb    = (const float*)d_in[2];
    const float* qkv_w = (const float*)d_in[3];
    const float* qkv_b = (const float*)d_in[4];
    const float* out_w = (const float*)d_in[5];
    const float* out_b = (const float*)d_in[6];
    float* out = (float*)d_out;
    char* ws = (char*)d_ws;

    const size_t MB = 1024 * 1024;
    f16*   qkvT   = (f16*)ws;                       // [8][1024][1024] q|k  (16 MB)
    f16*   XT     = (f16*)(ws + 16 * MB);           // blocked [8][32][1024][16] (8 MB)
    f16*   vbuf   = (f16*)(ws + 24 * MB);           // [8][512][1024] (j-permuted) (8 MB)
    f16*   w2T    = (f16*)(ws + 32 * MB);           // [8][1024][512]       (8 MB)
    f16*   Wq     = (f16*)(ws + 40 * MB);           // [1536][512]          (1.5 MB)
    f16*   Wo     = (f16*)(ws + 42 * MB);           // [512][512]           (0.5 MB)
    float* qkv_bs = (float*)(ws + 43 * MB);         // [1536]

    prep<<<dim3(256 + 4103), 256, 0, stream>>>(x, gw, gb, XT,
                                               qkv_w, out_w, qkv_b, Wq, Wo, qkv_bs);
    gemm_f16<false><<<dim3(768), 256, 0, stream>>>(Wq, XT, qkv_bs, (void*)qkvT, vbuf);
    attn_f16<<<dim3(512), 256, 0, stream>>>(qkvT, vbuf, w2T);
    gemm_f16<true><<<dim3(512), 256, 0, stream>>>(Wo, w2T, out_b, (void*)out, nullptr);
}